// Round 4
// baseline (932.248 us; speedup 1.0000x reference)
//
#include <hip/hip_runtime.h>
#include <hip/hip_bf16.h>
#include <cstddef>

// ---------------------------------------------------------------------------
// HGTConv, algebraically reduced:
//   softmax(scores).mean(-1) == 1/8 exactly  =>  attention path is dead code.
//   segment_sum is linear  =>
//     out = relu( mx @ (Wv@Wm@Wout)/8 + beta*((bv@Wm+bm)@Wout)/8 + bout + x )
//   with mx = segsum(x[src])/max(cnt,1), beta = (cnt>0).
//
// R1: scatter-atomics -> CSR build + gather-reduce.
// R2: fused aggregate+GEMM, bf16 MFMA, pre-swizzled B.
// R3: phase-1 was latency-bound (serial per-row chains, all pipes <20%).
//     -> edge-parallel gather into fp32 LDS tile via ds_add_f32 (local row id
//        packed in perm high bits), 1/deg deferred to epilogue, BR=32,
//        bank-balanced stride 260, merged launches (17 -> 10).
// ---------------------------------------------------------------------------

#define DD 256
#define BR 32
#define ASTRIDE 260  // floats; 260 % 32 == 4 -> bank-balanced for row writes + b128 frag reads

typedef __attribute__((ext_vector_type(8))) short short8;
typedef __attribute__((ext_vector_type(4))) float floatx4;

__device__ __forceinline__ short f2bf(float f) {
    union { float f; unsigned u; } c;
    c.f = f;
    unsigned r = c.u + 0x7fffu + ((c.u >> 16) & 1u);
    return (short)(r >> 16);
}

// convert 8 consecutive fp32 (16B-aligned) to bf16 short8 via packed cvt
__device__ __forceinline__ short8 cvt8(const float* p) {
    const float4 a = *(const float4*)p;
    const float4 b = *(const float4*)(p + 4);
    __hip_bfloat162 h0 = __float22bfloat162_rn(make_float2(a.x, a.y));
    __hip_bfloat162 h1 = __float22bfloat162_rn(make_float2(a.z, a.w));
    __hip_bfloat162 h2 = __float22bfloat162_rn(make_float2(b.x, b.y));
    __hip_bfloat162 h3 = __float22bfloat162_rn(make_float2(b.z, b.w));
    const short2 s0 = *(short2*)&h0, s1 = *(short2*)&h1;
    const short2 s2 = *(short2*)&h2, s3 = *(short2*)&h3;
    short8 r;
    r[0] = s0.x; r[1] = s0.y; r[2] = s1.x; r[3] = s1.y;
    r[4] = s2.x; r[5] = s2.y; r[6] = s3.x; r[7] = s3.y;
    return r;
}

// ---- weight fusion ----------------------------------------------------------
__global__ __launch_bounds__(256) void gemm256x2(const float* __restrict__ A0,
                                                 const float* __restrict__ B0,
                                                 float* __restrict__ C0,
                                                 const float* __restrict__ A1,
                                                 const float* __restrict__ B1,
                                                 float* __restrict__ C1) {
    __shared__ float As[DD];
    const int which = blockIdx.x >> 8;
    const int r = blockIdx.x & 255;
    const int c = threadIdx.x;
    const float* A = which ? A1 : A0;
    const float* B = which ? B1 : B0;
    float* C = which ? C1 : C0;
    As[c] = A[r * DD + c];
    __syncthreads();
    float acc = 0.f;
#pragma unroll 8
    for (int k = 0; k < DD; ++k) acc += As[k] * B[k * DD + c];
    C[r * DD + c] = acc;
}

// Wf = T@Wout * 0.125 emitted as bf16 in MFMA B-fragment order.
__global__ __launch_bounds__(256) void gemm256_swz_x2(const float* __restrict__ A0,
                                                      const float* __restrict__ B0,
                                                      short* __restrict__ C0,
                                                      const float* __restrict__ A1,
                                                      const float* __restrict__ B1,
                                                      short* __restrict__ C1) {
    __shared__ float As[DD];
    const int which = blockIdx.x >> 8;
    const int r = blockIdx.x & 255;  // k index
    const int c = threadIdx.x;       // n index
    const float* A = which ? A1 : A0;
    const float* B = which ? B1 : B0;
    short* C = which ? C1 : C0;
    As[c] = A[r * DD + c];
    __syncthreads();
    float acc = 0.f;
#pragma unroll 8
    for (int k = 0; k < DD; ++k) acc += As[k] * B[k * DD + c];
    const int idx = ((((r >> 5) * 16 + (c >> 4)) * 64 +
                      ((c & 15) | (((r >> 3) & 3) << 4))) << 3) + (r & 7);
    C[idx] = f2bf(acc * 0.125f);
}

__global__ __launch_bounds__(256) void bias_fuse2(const float* __restrict__ bv0,
                                                  const float* __restrict__ Wm0,
                                                  const float* __restrict__ bm0,
                                                  const float* __restrict__ Wout0,
                                                  float* __restrict__ bb0,
                                                  const float* __restrict__ bv1,
                                                  const float* __restrict__ Wm1,
                                                  const float* __restrict__ bm1,
                                                  const float* __restrict__ Wout1,
                                                  float* __restrict__ bb1) {
    __shared__ float t[DD];
    const int w = blockIdx.x;
    const float* bv = w ? bv1 : bv0;
    const float* Wm = w ? Wm1 : Wm0;
    const float* bm = w ? bm1 : bm0;
    const float* Wout = w ? Wout1 : Wout0;
    float* bb = w ? bb1 : bb0;
    const int c = threadIdx.x;
    float acc = bm[c];
#pragma unroll 8
    for (int k = 0; k < DD; ++k) acc += bv[k] * Wm[k * DD + c];
    t[c] = acc;
    __syncthreads();
    float acc2 = 0.f;
#pragma unroll 8
    for (int k = 0; k < DD; ++k) acc2 += t[k] * Wout[k * DD + c];
    bb[c] = acc2 * 0.125f;
}

// ---- CSR build (merged pairs) ----------------------------------------------
__global__ __launch_bounds__(256) void hist2(const int* __restrict__ dst_p, int Ep,
                                             int* __restrict__ cnt_g,
                                             const int* __restrict__ dst_r, int Er,
                                             int* __restrict__ cnt_u) {
    const int i = blockIdx.x * 256 + threadIdx.x;
    if (i < Ep) atomicAdd(&cnt_g[dst_p[i]], 1);
    else if (i < Ep + Er) atomicAdd(&cnt_u[dst_r[i - Ep]], 1);
}

#define SCAN_CHUNK 2048
__global__ __launch_bounds__(256) void scan_chunk2(int* __restrict__ off_g,
                                                   int* __restrict__ sums_g,
                                                   int n_g, int nch_g,
                                                   int* __restrict__ off_u,
                                                   int* __restrict__ sums_u, int n_u) {
    __shared__ int ls[256];
    const int b = blockIdx.x;
    int* off; int* sums; int n; int cb;
    if (b < nch_g) { off = off_g; sums = sums_g; n = n_g; cb = b; }
    else { off = off_u; sums = sums_u; n = n_u; cb = b - nch_g; }
    const int tid = threadIdx.x;
    const int base = cb * SCAN_CHUNK + tid * 8;
    int v[8];
    int s = 0;
#pragma unroll
    for (int i = 0; i < 8; ++i) {
        const int idx = base + i;
        v[i] = (idx < n) ? off[idx] : 0;
        s += v[i];
    }
    ls[tid] = s;
    __syncthreads();
    for (int d = 1; d < 256; d <<= 1) {
        const int t = (tid >= d) ? ls[tid - d] : 0;
        __syncthreads();
        ls[tid] += t;
        __syncthreads();
    }
    int excl = tid ? ls[tid - 1] : 0;
    if (tid == 255) sums[cb] = ls[255];
#pragma unroll
    for (int i = 0; i < 8; ++i) {
        const int idx = base + i;
        if (idx < n) off[idx] = excl;
        excl += v[i];
    }
}

__global__ __launch_bounds__(256) void scan_sums2(int* __restrict__ sums_g, int nch_g,
                                                  int* __restrict__ sums_u, int nch_u) {
    __shared__ int ls[256];
    int* sums = blockIdx.x ? sums_u : sums_g;
    const int nch = blockIdx.x ? nch_u : nch_g;
    const int tid = threadIdx.x;
    ls[tid] = (tid < nch) ? sums[tid] : 0;
    __syncthreads();
    for (int d = 1; d < 256; d <<= 1) {
        const int t = (tid >= d) ? ls[tid - d] : 0;
        __syncthreads();
        ls[tid] += t;
        __syncthreads();
    }
    if (tid < nch) sums[tid] = tid ? ls[tid - 1] : 0;
}

// adds chunk offsets, sets off[n]=E, and initializes cursor = off.
__global__ __launch_bounds__(256) void scan_add2(int* __restrict__ off_g,
                                                 const int* __restrict__ sums_g,
                                                 int* __restrict__ cur_g, int n_g, int Ep,
                                                 int* __restrict__ off_u,
                                                 const int* __restrict__ sums_u,
                                                 int* __restrict__ cur_u, int n_u, int Er) {
    const int i = blockIdx.x * 256 + threadIdx.x;
    if (i <= n_g) {
        if (i < n_g) {
            const int v = off_g[i] + sums_g[i / SCAN_CHUNK];
            off_g[i] = v;
            cur_g[i] = v;
        } else off_g[n_g] = Ep;
    } else {
        const int j = i - (n_g + 1);
        if (j < n_u) {
            const int v = off_u[j] + sums_u[j / SCAN_CHUNK];
            off_u[j] = v;
            cur_u[j] = v;
        } else if (j == n_u) off_u[n_u] = Er;
    }
}

// perm[pos] = src | ((dst & 31) << 20)  (local row within the BR=32 agg block)
__global__ __launch_bounds__(256) void permute2(const int* __restrict__ src_p,
                                                const int* __restrict__ dst_p, int Ep,
                                                int* __restrict__ cur_g,
                                                int* __restrict__ perm_p,
                                                const int* __restrict__ src_r,
                                                const int* __restrict__ dst_r, int Er,
                                                int* __restrict__ cur_u,
                                                int* __restrict__ perm_r) {
    const int i = blockIdx.x * 256 + threadIdx.x;
    if (i < Ep) {
        const int d = dst_p[i];
        const int pos = atomicAdd(&cur_g[d], 1);
        perm_p[pos] = src_p[i] | ((d & (BR - 1)) << 20);
    } else if (i < Ep + Er) {
        const int j = i - Ep;
        const int d = dst_r[j];
        const int pos = atomicAdd(&cur_u[d], 1);
        perm_r[pos] = src_r[j] | ((d & (BR - 1)) << 20);
    }
}

// ---- fused aggregate + bf16-MFMA GEMM + epilogue, both directions ----------
// Block = 32 dst rows, 256 threads (4 waves).
// Phase 1 (edge-parallel): waves stride the block's contiguous CSR edge range;
//   per edge: coalesced 1KB row gather + ds_add_f32 into fp32 LDS tile.
// Phase 2: wave w computes rows[0:32) x cols[w*64,+64) via mfma_f32_16x16x32_bf16;
//   A-frags cvt_pk'd from LDS f32 (raw sums), B-frags coalesced from swizzled Wf.
// Epilogue: *1/deg + beta*bb + bout + x, relu.
__global__ __launch_bounds__(256, 4) void agg_gemm2(
    const float* __restrict__ x_user, const float* __restrict__ x_game,
    const int* __restrict__ perm_rev, const int* __restrict__ off_user,
    const int* __restrict__ perm_played, const int* __restrict__ off_game,
    const short* __restrict__ Bsw_rev, const short* __restrict__ Bsw_played,
    const float* __restrict__ bb_rev, const float* __restrict__ bb_played,
    const float* __restrict__ bout_user, const float* __restrict__ bout_game,
    float* __restrict__ out_user, float* __restrict__ out_game,
    int n_user, int n_game, int nbu) {
    __shared__ float Asf[BR][ASTRIDE];
    __shared__ int offs[BR + 1];

    const int tid = threadIdx.x;
    const int wave = tid >> 6;
    const int lane = tid & 63;

    const float* x_src; const float* x_res; const int* perm; const int* off;
    const short* Bsw; const float* bb; const float* bout; float* outp;
    int M, r0;
    if ((int)blockIdx.x < nbu) {
        r0 = blockIdx.x * BR;
        M = n_user; x_src = x_game; x_res = x_user; perm = perm_rev;
        off = off_user; Bsw = Bsw_rev; bb = bb_rev; bout = bout_user; outp = out_user;
    } else {
        r0 = (blockIdx.x - nbu) * BR;
        M = n_game; x_src = x_user; x_res = x_game; perm = perm_played;
        off = off_game; Bsw = Bsw_played; bb = bb_played; bout = bout_game; outp = out_game;
    }

    // phase 0: zero tile + stage offsets
    float4* az = (float4*)&Asf[0][0];
    for (int i = tid; i < BR * ASTRIDE / 4; i += 256) az[i] = make_float4(0.f, 0.f, 0.f, 0.f);
    if (tid <= BR) offs[tid] = off[min(r0 + tid, M)];
    __syncthreads();

    // phase 1: edge-parallel gather-accumulate (unroll 2 for MLP)
    const int e1b = offs[BR];
    int e = offs[0] + wave;
    for (; e + 4 < e1b; e += 8) {
        const int p0 = perm[e];
        const int p1 = perm[e + 4];
        const int s0 = p0 & 0xFFFFF, lr0 = p0 >> 20;
        const int s1 = p1 & 0xFFFFF, lr1 = p1 >> 20;
        const float4 v0 = ((const float4*)(x_src + (size_t)s0 * DD))[lane];
        const float4 v1 = ((const float4*)(x_src + (size_t)s1 * DD))[lane];
        float* a0 = &Asf[lr0][lane * 4];
        float* a1 = &Asf[lr1][lane * 4];
        atomicAdd(a0 + 0, v0.x); atomicAdd(a0 + 1, v0.y);
        atomicAdd(a0 + 2, v0.z); atomicAdd(a0 + 3, v0.w);
        atomicAdd(a1 + 0, v1.x); atomicAdd(a1 + 1, v1.y);
        atomicAdd(a1 + 2, v1.z); atomicAdd(a1 + 3, v1.w);
    }
    for (; e < e1b; e += 4) {
        const int p = perm[e];
        const int s = p & 0xFFFFF, lr = p >> 20;
        const float4 v = ((const float4*)(x_src + (size_t)s * DD))[lane];
        float* a = &Asf[lr][lane * 4];
        atomicAdd(a + 0, v.x); atomicAdd(a + 1, v.y);
        atomicAdd(a + 2, v.z); atomicAdd(a + 3, v.w);
    }
    __syncthreads();

    // phase 2: MFMA (wave owns cols [wave*64, wave*64+64))
    const int quad = lane >> 4;
    const int l16 = lane & 15;
    floatx4 acc[2][4];
#pragma unroll
    for (int rt = 0; rt < 2; ++rt)
#pragma unroll
        for (int ct = 0; ct < 4; ++ct) acc[rt][ct] = (floatx4){0.f, 0.f, 0.f, 0.f};

    for (int kb8 = 0; kb8 < 8; ++kb8) {
        short8 af[2];
#pragma unroll
        for (int rt = 0; rt < 2; ++rt)
            af[rt] = cvt8(&Asf[rt * 16 + l16][kb8 * 32 + quad * 8]);
        short8 bf[4];
        const short* bp = Bsw + (((size_t)(kb8 * 16 + wave * 4) * 64 + lane) << 3);
#pragma unroll
        for (int ct = 0; ct < 4; ++ct)
            bf[ct] = *(const short8*)(bp + (ct << 9));
#pragma unroll
        for (int rt = 0; rt < 2; ++rt)
#pragma unroll
            for (int ct = 0; ct < 4; ++ct)
                acc[rt][ct] = __builtin_amdgcn_mfma_f32_16x16x32_bf16(
                    af[rt], bf[ct], acc[rt][ct], 0, 0, 0);
    }

    // epilogue
    float bbv[4], bov[4];
#pragma unroll
    for (int ct = 0; ct < 4; ++ct) {
        const int n = wave * 64 + ct * 16 + l16;
        bbv[ct] = bb[n];
        bov[ct] = bout[n];
    }
#pragma unroll
    for (int rt = 0; rt < 2; ++rt) {
#pragma unroll
        for (int j = 0; j < 4; ++j) {
            const int lr = rt * 16 + quad * 4 + j;
            const int r = r0 + lr;
            if (r < M) {
                const int dg = offs[lr + 1] - offs[lr];
                const float inv = 1.0f / fmaxf((float)dg, 1.0f);
                const float btv = (dg > 0) ? 1.0f : 0.0f;
                const float* xr = x_res + (size_t)r * DD;
                float* orow = outp + (size_t)r * DD;
#pragma unroll
                for (int ct = 0; ct < 4; ++ct) {
                    const int n = wave * 64 + ct * 16 + l16;
                    const float o = acc[rt][ct][j] * inv + btv * bbv[ct] + bov[ct] + xr[n];
                    orow[n] = fmaxf(o, 0.f);
                }
            }
        }
    }
}

extern "C" void kernel_launch(void* const* d_in, const int* in_sizes, int n_in,
                              void* d_out, int out_size, void* d_ws, size_t ws_size,
                              hipStream_t stream) {
    const float* x_user = (const float*)d_in[0];
    const float* x_game = (const float*)d_in[1];
    const float* Wv_user = (const float*)d_in[6];
    const float* bv_user = (const float*)d_in[7];
    const float* Wout_user = (const float*)d_in[8];
    const float* bout_user = (const float*)d_in[9];
    const float* Wv_game = (const float*)d_in[14];
    const float* bv_game = (const float*)d_in[15];
    const float* Wout_game = (const float*)d_in[16];
    const float* bout_game = (const float*)d_in[17];
    const float* Wm_played = (const float*)d_in[20];
    const float* bm_played = (const float*)d_in[21];
    const float* Wm_rev = (const float*)d_in[24];
    const float* bm_rev = (const float*)d_in[25];
    const int* ei_played_src = (const int*)d_in[26];
    const int* ei_played_dst = (const int*)d_in[27];
    const int* ei_rev_src = (const int*)d_in[28];
    const int* ei_rev_dst = (const int*)d_in[29];

    const int n_user = in_sizes[0] / DD;
    const int n_game = in_sizes[1] / DD;
    const int e_played = in_sizes[26];
    const int e_rev = in_sizes[28];

    float* out = (float*)d_out;
    float* out_user = out;
    float* out_game = out + (size_t)n_user * DD;

    // ---- workspace layout ----
    float* fws = (float*)d_ws;
    float* T0 = fws;                       // 64K f32
    float* T1 = T0 + DD * DD;              // 64K f32
    float* bb_played = T1 + DD * DD;       // 256
    float* bb_rev = bb_played + DD;        // 256
    short* Bsw_played = (short*)(bb_rev + DD);   // 64K bf16
    short* Bsw_rev = Bsw_played + DD * DD;       // 64K bf16
    int* iws = (int*)(Bsw_rev + DD * DD);
    int* off_game = iws;                      // n_game+1
    int* off_user = off_game + (n_game + 1);  // n_user+1
    int* cursor_game = off_user + (n_user + 1);
    int* cursor_user = cursor_game + n_game;
    int* sums_game = cursor_user + n_user;    // 256
    int* sums_user = sums_game + 256;         // 256
    int* perm_played = sums_user + 256;       // E
    int* perm_rev = perm_played + e_played;   // E
    (void)ws_size; (void)n_in; (void)out_size;

    hipMemsetAsync(off_game, 0, (size_t)(n_game + n_user + 2) * sizeof(int), stream);

    // weight fusion
    gemm256x2<<<512, DD, 0, stream>>>(Wv_user, Wm_played, T0, Wv_game, Wm_rev, T1);
    gemm256_swz_x2<<<512, DD, 0, stream>>>(T0, Wout_game, Bsw_played,
                                           T1, Wout_user, Bsw_rev);
    bias_fuse2<<<2, DD, 0, stream>>>(bv_user, Wm_played, bm_played, Wout_game, bb_played,
                                     bv_game, Wm_rev, bm_rev, Wout_user, bb_rev);

    // CSR build
    const int nch_g = (n_game + SCAN_CHUNK - 1) / SCAN_CHUNK;
    const int nch_u = (n_user + SCAN_CHUNK - 1) / SCAN_CHUNK;
    const int e_tot = e_played + e_rev;
    hist2<<<(e_tot + 255) / 256, 256, 0, stream>>>(ei_played_dst, e_played, off_game,
                                                   ei_rev_dst, e_rev, off_user);
    scan_chunk2<<<nch_g + nch_u, 256, 0, stream>>>(off_game, sums_game, n_game, nch_g,
                                                   off_user, sums_user, n_user);
    scan_sums2<<<2, 256, 0, stream>>>(sums_game, nch_g, sums_user, nch_u);
    scan_add2<<<(n_game + n_user + 2 + 255) / 256, 256, 0, stream>>>(
        off_game, sums_game, cursor_game, n_game, e_played,
        off_user, sums_user, cursor_user, n_user, e_rev);
    permute2<<<(e_tot + 255) / 256, 256, 0, stream>>>(
        ei_played_src, ei_played_dst, e_played, cursor_game, perm_played,
        ei_rev_src, ei_rev_dst, e_rev, cursor_user, perm_rev);

    // fused aggregate + GEMM + epilogue (both directions, one dispatch)
    const int nbu = (n_user + BR - 1) / BR;
    const int nbg = (n_game + BR - 1) / BR;
    agg_gemm2<<<nbu + nbg, 256, 0, stream>>>(
        x_user, x_game, perm_rev, off_user, perm_played, off_game,
        Bsw_rev, Bsw_played, bb_rev, bb_played, bout_user, bout_game,
        out_user, out_game, n_user, n_game, nbu);
}